// Round 14
// baseline (700.338 us; speedup 1.0000x reference)
//
#include <hip/hip_runtime.h>
#include <math.h>

#define BB 64
#define NN 512
#define KK 16

// ---------------------------------------------------------------------------
// GELU helpers
// ---------------------------------------------------------------------------
__device__ __forceinline__ float gelu32(float x) {
    return 0.5f * x * (1.0f + erff(x * 0.70710678118654752440f));
}

// Table-based f64 GELU: erf(z) via nearest-node cubic Taylor, h = 1/64.
// Covers z <= 4.07 (|x| < 5.74); abs err ~8e-10 in range, ~3e-8 at the tail
// cutoff — ~1e7x below the knn2 rank-gap scale and invisible at bf16.
#define TAB_N 261
__device__ __forceinline__ double gelu64_tab(double x, const double2* s_tab) {
    double ax = fabs(x);
    if (ax >= 5.74) return x > 0.0 ? x : 0.0;
    double z = ax * 0.70710678118654752440;
    double u = z * 64.0;
    int i = (int)(u + 0.5);
    double zi = (double)i * (1.0 / 64.0);
    double d = z - zi;
    double2 t = s_tab[i];
    // erf(zi + d) = E + G*(d - zi*d^2 + (2*zi^2-1)/3 * d^3)
    double poly = d * (1.0 + d * (-zi + d * ((2.0 * zi * zi - 1.0) * (1.0 / 3.0))));
    double er = t.x + t.y * poly;
    double s = (x > 0.0) ? er : -er;
    return 0.5 * x * (1.0 + s);
}

// ---------------------------------------------------------------------------
// Wave-local top-17 extraction from 8 register-resident candidates per lane.
// No LDS, no barriers. Tie-break: lexicographic (dist, index), identical to
// jax.lax.top_k on negated distances. Winner-removal uses compile-time
// indices only (runtime-indexed reg arrays go to scratch — rule #20).
// ---------------------------------------------------------------------------
#define SELECT_TOP17(d, lane, OUT_STMT)                                        \
    for (int it = 0; it <= KK; ++it) {                                         \
        double bd = d[0];                                                      \
        int bi = lane;                                                         \
        _Pragma("unroll")                                                      \
        for (int i = 1; i < 8; ++i) {                                          \
            int m = lane + 64 * i;                                             \
            if (d[i] < bd) { bd = d[i]; bi = m; }                              \
        }                                                                      \
        for (int off = 32; off > 0; off >>= 1) {                               \
            double od = __shfl_xor(bd, off, 64);                               \
            int    oi = __shfl_xor(bi, off, 64);                               \
            if (od < bd || (od == bd && oi < bi)) { bd = od; bi = oi; }        \
        }                                                                      \
        const int wl = bi & 63, wsl = bi >> 6;                                 \
        _Pragma("unroll")                                                      \
        for (int i = 0; i < 8; ++i)                                            \
            if (lane == wl && i == wsl) d[i] = 1e300;                          \
        if (it > 0 && lane == 0) { OUT_STMT; }                                 \
    }

// ---------------------------------------------------------------------------
// Fused block-1 kNN + U1/T1 projections + compaction + table + W2d convert.
// Blocks [0, 4096): knn1 (8 queries per 512-thread block).
// Blocks [4096, 4096+uvb): per-row projections —
//   U1[row][j] = sum_c x[row][c]*W1a[c][j]          (f64)
//   T1[row][j] = b1[j] + sum_c x[row][c]*(W1b-W1a)  (f64, tier 2 only; same
//   accumulation order as the old in-mlp1 tn -> bit-identical)
// Next 64 blocks: order-preserving compaction of unmasked indices per batch.
// Next block: erf table build. Last block (tier 2): W2 -> f64 copy.
// ---------------------------------------------------------------------------
__global__ __launch_bounds__(512) void knn1_uv1(const float* __restrict__ points,
                                                const int* __restrict__ mask,
                                                const float* __restrict__ x,
                                                const float* __restrict__ W1,
                                                const float* __restrict__ b1,
                                                const float* __restrict__ W2,
                                                int uvb, int tier,
                                                int* __restrict__ idx_out,
                                                double* __restrict__ U1,
                                                double* __restrict__ T1,
                                                double* __restrict__ W2d,
                                                int* __restrict__ cu,
                                                int* __restrict__ nU,
                                                double2* __restrict__ g_tab) {
    __shared__ double sbuf[3 * NN];    // 12 KB
    const int tid = threadIdx.x;
    const int knnb = BB * NN / 8;

    if (blockIdx.x < knnb) {
        double (*pts)[NN] = (double (*)[NN])sbuf;
        const int b = blockIdx.x >> 6;          // 64 blocks per batch
        const int n0 = (blockIdx.x & 63) * 8;
        const int w = tid >> 6, lane = tid & 63;

        for (int e = tid; e < NN; e += 512) {
            double sh = (mask[b * NN + e] == 0) ? 999.0 : 0.0;
            const float* p = points + ((size_t)b * NN + e) * 3;
            pts[0][e] = (double)p[0] + sh;
            pts[1][e] = (double)p[1] + sh;
            pts[2][e] = (double)p[2] + sh;
        }
        __syncthreads();

        const int n = n0 + w;
        if (mask[b * NN + n] == 0) return;   // wave-uniform; no barriers below
        const double q0 = pts[0][n], q1 = pts[1][n], q2 = pts[2][n];
        double d[8];
        #pragma unroll
        for (int i = 0; i < 8; ++i) {
            int m = lane + 64 * i;
            double d0 = q0 - pts[0][m], d1 = q1 - pts[1][m], d2 = q2 - pts[2][m];
            d[i] = d0 * d0 + d1 * d1 + d2 * d2;   // +1e-5 const: ordering-invariant
        }

        int* orow = idx_out + (size_t)(b * NN + n) * KK;
        SELECT_TOP17(d, lane, orow[it - 1] = bi)
    } else if (blockIdx.x < knnb + uvb) {
        // uv1: rows row0..row0+7
        double (*xs)[32] = (double (*)[32])sbuf;
        const int row0 = (blockIdx.x - knnb) * 8;
        if (tid < 256) xs[tid >> 5][tid & 31] = (double)x[(size_t)row0 * 32 + tid];
        __syncthreads();
        const int j = tid & 127;
        const int rr = tid >> 7;                 // 0..3, wave-uniform (2 waves/row)
        #pragma unroll
        for (int p = 0; p < 2; ++p) {
            const int r = p * 4 + rr;
            const int row = row0 + r;
            if (mask[row] != 0) {
                if (tier == 2) {
                    double au = 0.0, at = (double)b1[j];
                    #pragma unroll 4
                    for (int c = 0; c < 32; ++c) {
                        double xv = xs[r][c];
                        double wa = (double)W1[c * 128 + j];
                        double wb = (double)W1[(32 + c) * 128 + j];
                        au += xv * wa;
                        at += xv * (wb - wa);
                    }
                    U1[(size_t)row * 128 + j] = au;
                    T1[(size_t)row * 128 + j] = at;
                } else {
                    double acc = 0.0;
                    #pragma unroll 4
                    for (int c = 0; c < 32; ++c)
                        acc += xs[r][c] * (double)W1[c * 128 + j];
                    U1[(size_t)row * 128 + j] = acc;
                }
            }
        }
    } else if (blockIdx.x < knnb + uvb + BB) {
        // compaction: one batch per block, 512 threads = 512 candidates
        __shared__ int wcnt[8], woff[8];
        const int b = blockIdx.x - (knnb + uvb);
        const int w = tid >> 6, lane = tid & 63;
        const int bit = (mask[b * NN + tid] != 0) ? 1 : 0;
        unsigned long long bal = __ballot(bit);
        int pos = __popcll(bal & ((1ull << lane) - 1ull));
        if (lane == 0) wcnt[w] = __popcll(bal);
        __syncthreads();
        if (tid == 0) {
            int acc = 0;
            #pragma unroll
            for (int i = 0; i < 8; ++i) { woff[i] = acc; acc += wcnt[i]; }
            nU[b] = acc;
        }
        __syncthreads();
        if (bit) cu[b * NN + woff[w] + pos] = tid;
    } else if (blockIdx.x < knnb + uvb + BB + 1) {
        // erf table build
        for (int i = tid; i < TAB_N; i += 512) {
            double z = (double)i * (1.0 / 64.0);
            double2 e;
            e.x = erf(z);
            e.y = 1.12837916709551257390 * exp(-z * z);  // 2/sqrt(pi)*exp(-z^2)
            g_tab[i] = e;
        }
    } else {
        // tier 2: W2 -> f64 copy (exact; kills per-load v_cvt in mlp1 layer 2)
        for (int e = tid; e < 128 * 64; e += 512) W2d[e] = (double)W2[e];
    }
}

// ---------------------------------------------------------------------------
// Block-1 MLP in f64 (LDS-table GELU) + fused rm + fused U2/T2 projections.
// Masked rows: exit immediately (never candidates after compaction).
// UV=2: layer 1 = gather U1[m] + T1[bn] (tn loop + ctr deleted); layer 2
//        loads W2d f64 (no converts); epilogue computes U2 AND T2 rows
//        (half-block each, concurrent).
// UV=1: round-13 form. UV=0: edge-gather fallback.
// Layer 2 (all tiers): scalar-j, double2 H1 reads — validated optimum
// (j-tiling variants regressed, rounds 11/12).
// LDS (UV=2) ~22.9 KB -> 7 blocks/CU.
// ---------------------------------------------------------------------------
template<int UV>
__global__ __launch_bounds__(256, 2) void mlp1_f64(const float* __restrict__ x,
                                                   const int* __restrict__ idx,
                                                   const float* __restrict__ W1,
                                                   const float* __restrict__ b1,
                                                   const float* __restrict__ W2,
                                                   const float* __restrict__ b2,
                                                   const float* __restrict__ W1n, // W1_1
                                                   const float* __restrict__ b1n, // b1_1
                                                   const double2* __restrict__ g_tab,
                                                   const int* __restrict__ mask,
                                                   const double* __restrict__ U1,
                                                   const double* __restrict__ T1,
                                                   const double* __restrict__ W2d,
                                                   double* __restrict__ feats_out,
                                                   double* __restrict__ rm,
                                                   float* __restrict__ U2,
                                                   float* __restrict__ T2) {
    const int C = 32;
    __shared__ double2 s_tab[TAB_N];               // 4.2 KB
    __shared__ __align__(16) double H1[KK][128];   // 16 KB
    __shared__ double part[4][64];                 //  2 KB
    __shared__ float f_row[64];                    // 256 B
    const int swz = ((blockIdx.x & 7) << 12) + (blockIdx.x >> 3);  // 32768/8 = 4096
    const int b = swz >> 9;
    const int bn = swz;
    const int tid = threadIdx.x;

    if (mask[bn] == 0) return;         // block-uniform; nothing downstream reads

    for (int i = tid; i < TAB_N; i += 256) s_tab[i] = g_tab[i];

    if constexpr (UV == 2) {
        __syncthreads();
        const int j = tid & 127;
        const int kb = (tid >> 7) * 8;
        double tn = T1[(size_t)bn * 128 + j];
        #pragma unroll
        for (int kk = 0; kk < 8; ++kk) {
            int m = idx[bn * KK + kb + kk];
            double v = U1[(size_t)(b * NN + m) * 128 + j] + tn;
            H1[kb + kk][j] = gelu64_tab(v, s_tab);
        }
    } else if constexpr (UV == 1) {
        __shared__ double ctr[32];
        if (tid < C) ctr[tid] = (double)x[(size_t)bn * C + tid];
        __syncthreads();
        const int j = tid & 127;
        const int kb = (tid >> 7) * 8;
        double tn = (double)b1[j];
        #pragma unroll 4
        for (int c = 0; c < C; ++c)
            tn += ctr[c] * ((double)W1[(C + c) * 128 + j] - (double)W1[c * 128 + j]);
        #pragma unroll
        for (int kk = 0; kk < 8; ++kk) {
            int m = idx[bn * KK + kb + kk];
            double v = U1[(size_t)(b * NN + m) * 128 + j] + tn;
            H1[kb + kk][j] = gelu64_tab(v, s_tab);
        }
    } else {
        __shared__ double ctr[32];
        __shared__ double edg[KK][32];
        if (tid < C) ctr[tid] = (double)x[(size_t)bn * C + tid];
        __syncthreads();
        for (int e = tid; e < KK * C; e += 256) {
            int k = e >> 5, c = e & 31;
            int m = idx[bn * KK + k];
            edg[k][c] = (double)x[((size_t)b * NN + m) * C + c] - ctr[c];
        }
        __syncthreads();
        const int j = tid & 127;
        const int kb = (tid >> 7) * 8;
        double cterm = (double)b1[j];
        #pragma unroll 2
        for (int c = 0; c < C; ++c) cterm += ctr[c] * (double)W1[(C + c) * 128 + j];
        double acc[8];
        #pragma unroll
        for (int kk = 0; kk < 8; ++kk) acc[kk] = cterm;
        #pragma unroll 2
        for (int c = 0; c < C; ++c) {
            double w = (double)W1[c * 128 + j];
            #pragma unroll
            for (int kk = 0; kk < 8; ++kk) acc[kk] += edg[kb + kk][c] * w;
        }
        #pragma unroll
        for (int kk = 0; kk < 8; ++kk) H1[kb + kk][j] = gelu64_tab(acc[kk], s_tab);
    }
    __syncthreads();

    {   // layer 2: thread -> (j = tid&63, k-group g = tid>>6 of 4).
        // double2 H1 reads over c-pairs; per-acc accumulation order unchanged.
        const int j = tid & 63;
        const int g = tid >> 6;
        const int kb = g * 4;
        double acc[4];
        #pragma unroll
        for (int kk = 0; kk < 4; ++kk) acc[kk] = (double)b2[j];
        #pragma unroll 2
        for (int c = 0; c < 128; c += 2) {
            double w0, w1;
            if constexpr (UV == 2) {
                w0 = W2d[c * 64 + j];
                w1 = W2d[(c + 1) * 64 + j];
            } else {
                w0 = (double)W2[c * 64 + j];
                w1 = (double)W2[(c + 1) * 64 + j];
            }
            double2 h0 = *(const double2*)&H1[kb + 0][c];
            double2 h1 = *(const double2*)&H1[kb + 1][c];
            double2 h2 = *(const double2*)&H1[kb + 2][c];
            double2 h3 = *(const double2*)&H1[kb + 3][c];
            acc[0] += h0.x * w0; acc[0] += h0.y * w1;
            acc[1] += h1.x * w0; acc[1] += h1.y * w1;
            acc[2] += h2.x * w0; acc[2] += h2.y * w1;
            acc[3] += h3.x * w0; acc[3] += h3.y * w1;
        }
        double s = 0.0;
        #pragma unroll
        for (int kk = 0; kk < 4; ++kk) s += gelu64_tab(acc[kk], s_tab);
        part[g][j] = s;
    }
    __syncthreads();

    if (tid < 64) {   // wave 0: epilogue + fused rm (row is unmasked: sh=0)
        double s = (part[0][tid] + part[1][tid] + part[2][tid] + part[3][tid]) * 0.0625;
        feats_out[(size_t)bn * 64 + tid] = s;
        f_row[tid] = (float)s;
        double s2 = s * s;
        for (int off = 32; off > 0; off >>= 1) s2 += __shfl_xor(s2, off, 64);
        if (tid == 0) rm[bn] = s2;
    }
    if constexpr (UV == 2) {
        // fused uv2: half-block computes U2 row, other half T2 row.
        __syncthreads();
        const int j = tid & 127;
        if (tid < 128) {
            float acc = 0.0f;
            #pragma unroll 4
            for (int c = 0; c < 64; ++c) acc += f_row[c] * W1n[c * 128 + j];
            U2[(size_t)bn * 128 + j] = acc;
        } else {
            float acc = b1n[j];
            #pragma unroll 4
            for (int c = 0; c < 64; ++c)
                acc += f_row[c] * (W1n[(64 + c) * 128 + j] - W1n[c * 128 + j]);
            T2[(size_t)bn * 128 + j] = acc;
        }
    } else if constexpr (UV == 1) {
        __syncthreads();
        if (tid < 128) {
            float acc = 0.0f;
            #pragma unroll 4
            for (int c = 0; c < 64; ++c) acc += f_row[c] * W1n[c * 128 + tid];
            U2[(size_t)bn * 128 + tid] = acc;
        }
    }
}

// ---------------------------------------------------------------------------
// Block-2 kNN over COMPACTED unmasked candidates: F=64 f64 feats, top-17
// drop-first. 8 queries per 512-thread block; ~4 tiles (nU ~ 256). All
// candidates unmasked -> no shift terms; distances bit-identical to the
// uncompacted formula. Compacted order ascending -> tie-break identical.
// ---------------------------------------------------------------------------
__global__ __launch_bounds__(512) void knn2(const double* __restrict__ feats,
                                            const int* __restrict__ mask,
                                            const double* __restrict__ rm,
                                            const int* __restrict__ cu,
                                            const int* __restrict__ nU,
                                            int* __restrict__ idx_out) {
    __shared__ double tileT[64][65];   // [f][c], 33.3 KB
    __shared__ double qsh[8][64];      // 4 KB
    __shared__ double qrn[8];
    __shared__ int cI[NN];             // 2 KB
    __shared__ int s_nU;
    const int bid = ((blockIdx.x & 7) << 9) + (blockIdx.x >> 3);  // 4096/8 = 512
    const int b = bid >> 6;
    const int n0 = (bid & 63) * 8;
    const int tid = threadIdx.x;
    const int w = tid >> 6, lane = tid & 63;
    const int n = n0 + w;
    const int qm = mask[b * NN + n];   // wave-uniform

    if (tid == 0) s_nU = nU[b];
    for (int e = tid; e < NN; e += 512) cI[e] = cu[b * NN + e];
    qsh[w][lane] = feats[(size_t)(b * NN + n) * 64 + lane];
    if (lane == 0) qrn[w] = rm[b * NN + n];
    __syncthreads();

    const int nUl = s_nU;               // block-uniform
    const int ntiles = (nUl + 63) >> 6;

    double d[8];
    #pragma unroll
    for (int t = 0; t < 8; ++t) {
        d[t] = 1e300;
        if (t < ntiles) {               // block-uniform condition
            #pragma unroll
            for (int i = 0; i < 8; ++i) {
                int e = tid + 512 * i;
                int f = e & 63, c = e >> 6;
                int slot = t * 64 + c;
                if (slot < nUl)
                    tileT[f][c] = feats[(size_t)(b * NN + cI[slot]) * 64 + f];
            }
            __syncthreads();
            int slot = t * 64 + lane;
            if (qm && slot < nUl) {
                double a0 = 0.0, a1 = 0.0, a2 = 0.0, a3 = 0.0;
                for (int f = 0; f < 64; f += 4) {
                    a0 += qsh[w][f + 0] * tileT[f + 0][lane];
                    a1 += qsh[w][f + 1] * tileT[f + 1][lane];
                    a2 += qsh[w][f + 2] * tileT[f + 2][lane];
                    a3 += qsh[w][f + 3] * tileT[f + 3][lane];
                }
                double dot = (a0 + a1) + (a2 + a3);
                d[t] = qrn[w] + rm[b * NN + cI[slot]] - 2.0 * dot + 1e-5;
            }
            __syncthreads();
        }
    }

    if (qm) {
        int* orow = idx_out + (size_t)(b * NN + n) * KK;
        SELECT_TOP17(d, lane, orow[it - 1] = cI[bi])
    }
}

// ---------------------------------------------------------------------------
// Block-2 MLP in f32 + mean. Masked rows: write zeros, skip all compute.
// UV=2: layer 1 = gather U2[m] + T2[bn] (ctr/feats read + tn loop deleted).
// Layer 2 (all tiers): round-10 float4 form (validated fastest).
// ---------------------------------------------------------------------------
template<int UV>
__global__ __launch_bounds__(256, 2) void mlp2_f32(const double* __restrict__ feats,
                                                   const int* __restrict__ idx,
                                                   const float* __restrict__ W1,
                                                   const float* __restrict__ b1,
                                                   const float* __restrict__ W2,
                                                   const float* __restrict__ b2,
                                                   const int* __restrict__ mask,
                                                   const float* __restrict__ U2,
                                                   const float* __restrict__ T2,
                                                   float* __restrict__ out) {
    const int C = 64;
    __shared__ __align__(16) float H1[KK][128];
    __shared__ float part[4][64];
    const int swz = ((blockIdx.x & 7) << 12) + (blockIdx.x >> 3);
    const int b = swz >> 9;
    const int bn = swz;
    const int tid = threadIdx.x;

    if (mask[bn] == 0) {               // block-uniform early exit
        if (tid < 64) out[(size_t)bn * 64 + tid] = 0.0f;
        return;
    }

    if constexpr (UV == 2) {
        const int j = tid & 127;
        const int kb = (tid >> 7) * 8;
        float tn = T2[(size_t)bn * 128 + j];
        #pragma unroll
        for (int kk = 0; kk < 8; ++kk) {
            int m = idx[bn * KK + kb + kk];
            H1[kb + kk][j] = gelu32(U2[(size_t)(b * NN + m) * 128 + j] + tn);
        }
    } else if constexpr (UV == 1) {
        __shared__ float ctr[64];
        if (tid < C) ctr[tid] = (float)feats[(size_t)bn * C + tid];
        __syncthreads();
        const int j = tid & 127;
        const int kb = (tid >> 7) * 8;
        float tn = b1[j];
        #pragma unroll 4
        for (int c = 0; c < C; ++c)
            tn += ctr[c] * (W1[(C + c) * 128 + j] - W1[c * 128 + j]);
        #pragma unroll
        for (int kk = 0; kk < 8; ++kk) {
            int m = idx[bn * KK + kb + kk];
            H1[kb + kk][j] = gelu32(U2[(size_t)(b * NN + m) * 128 + j] + tn);
        }
    } else {
        __shared__ float ctr[64];
        __shared__ float edg[KK][64];
        if (tid < C) ctr[tid] = (float)feats[(size_t)bn * C + tid];
        __syncthreads();
        for (int e = tid; e < KK * C; e += 256) {
            int k = e >> 6, c = e & 63;
            int m = idx[bn * KK + k];
            edg[k][c] = (float)feats[((size_t)b * NN + m) * C + c] - ctr[c];
        }
        __syncthreads();
        const int j = tid & 127;
        const int kb = (tid >> 7) * 8;
        float cterm = b1[j];
        #pragma unroll 2
        for (int c = 0; c < C; ++c) cterm += ctr[c] * W1[(C + c) * 128 + j];
        float acc[8];
        #pragma unroll
        for (int kk = 0; kk < 8; ++kk) acc[kk] = cterm;
        #pragma unroll 2
        for (int c = 0; c < C; ++c) {
            float w = W1[c * 128 + j];
            #pragma unroll
            for (int kk = 0; kk < 8; ++kk) acc[kk] += edg[kb + kk][c] * w;
        }
        #pragma unroll
        for (int kk = 0; kk < 8; ++kk) H1[kb + kk][j] = gelu32(acc[kk]);
    }
    __syncthreads();

    {   // layer 2 (round-10): float4 H1 reads over c-quads; order preserved.
        const int j = tid & 63;
        const int g = tid >> 6;
        const int kb = g * 4;
        float acc[4];
        #pragma unroll
        for (int kk = 0; kk < 4; ++kk) acc[kk] = b2[j];
        #pragma unroll 2
        for (int c = 0; c < 128; c += 4) {
            float w0 = W2[(c + 0) * 64 + j];
            float w1 = W2[(c + 1) * 64 + j];
            float w2 = W2[(c + 2) * 64 + j];
            float w3 = W2[(c + 3) * 64 + j];
            #pragma unroll
            for (int kk = 0; kk < 4; ++kk) {
                float4 h = *(const float4*)&H1[kb + kk][c];
                acc[kk] += h.x * w0; acc[kk] += h.y * w1;
                acc[kk] += h.z * w2; acc[kk] += h.w * w3;
            }
        }
        float s = 0.0f;
        #pragma unroll
        for (int kk = 0; kk < 4; ++kk) s += gelu32(acc[kk]);
        part[g][j] = s;
    }
    __syncthreads();

    if (tid < 64) {
        float s = (part[0][tid] + part[1][tid] + part[2][tid] + part[3][tid]) * 0.0625f;
        out[(size_t)bn * 64 + tid] = s;
    }
}

extern "C" void kernel_launch(void* const* d_in, const int* in_sizes, int n_in,
                              void* d_out, int out_size, void* d_ws, size_t ws_size,
                              hipStream_t stream) {
    const float* x      = (const float*)d_in[0];
    const float* points = (const float*)d_in[1];
    const int*   mask   = (const int*)d_in[2];
    const float* W1_0 = (const float*)d_in[3];
    const float* b1_0 = (const float*)d_in[4];
    const float* W2_0 = (const float*)d_in[5];
    const float* b2_0 = (const float*)d_in[6];
    const float* W1_1 = (const float*)d_in[7];
    const float* b1_1 = (const float*)d_in[8];
    const float* W2_1 = (const float*)d_in[9];
    const float* b2_1 = (const float*)d_in[10];

    char* ws = (char*)d_ws;
    const size_t off_tab   = 0;                      //   16 KB reserved
    const size_t off_idx   = 16384;                  //    2 MB
    const size_t off_feats = off_idx + 2097152;      // 16.8 MB
    const size_t off_rm    = off_feats + 16777216;   //  256 KB
    const size_t off_cu    = off_rm + 262144;        //  128 KB
    const size_t off_nu    = off_cu + 131072;        //    4 KB
    const size_t off_u1    = off_nu + 4096;          // 33.5 MB
    const size_t off_u2    = off_u1 + 33554432;      // 16.8 MB
    const size_t need1     = off_u2 + 16777216;      // ~69.6 MB
    const size_t off_t1    = need1;                  // 33.5 MB
    const size_t off_t2    = off_t1 + 33554432;      // 16.8 MB
    const size_t off_w2d   = off_t2 + 16777216;      //   64 KB
    const size_t need2     = off_w2d + 65536;        // ~120 MB

    double2* tab    = (double2*)(ws + off_tab);
    int*     idx    = (int*)(ws + off_idx);
    double*  feats1 = (double*)(ws + off_feats);
    double*  rm     = (double*)(ws + off_rm);
    int*     cu     = (int*)(ws + off_cu);
    int*     nU     = (int*)(ws + off_nu);
    double*  U1     = (double*)(ws + off_u1);
    float*   U2     = (float*)(ws + off_u2);
    double*  T1     = (double*)(ws + off_t1);
    float*   T2     = (float*)(ws + off_t2);
    double*  W2d    = (double*)(ws + off_w2d);

    const int tier = (ws_size >= need2) ? 2 : ((ws_size >= need1) ? 1 : 0);
    const int uvb = tier ? BB * NN / 8 : 0;
    const int extra = (tier == 2) ? 2 : 1;           // tab (+ W2d convert)
    const int grid1 = BB * NN / 8 + uvb + BB + extra;

    knn1_uv1<<<grid1, 512, 0, stream>>>(points, mask, x, W1_0, b1_0, W2_0, uvb, tier,
                                        idx, U1, T1, W2d, cu, nU, tab);
    if (tier == 2) {
        mlp1_f64<2><<<BB * NN, 256, 0, stream>>>(x, idx, W1_0, b1_0, W2_0, b2_0,
                                                 W1_1, b1_1, tab, mask, U1, T1, W2d,
                                                 feats1, rm, U2, T2);
        knn2<<<BB * NN / 8, 512, 0, stream>>>(feats1, mask, rm, cu, nU, idx);
        mlp2_f32<2><<<BB * NN, 256, 0, stream>>>(feats1, idx, W1_1, b1_1, W2_1, b2_1,
                                                 mask, U2, T2, (float*)d_out);
    } else if (tier == 1) {
        mlp1_f64<1><<<BB * NN, 256, 0, stream>>>(x, idx, W1_0, b1_0, W2_0, b2_0,
                                                 W1_1, b1_1, tab, mask, U1, T1, W2d,
                                                 feats1, rm, U2, T2);
        knn2<<<BB * NN / 8, 512, 0, stream>>>(feats1, mask, rm, cu, nU, idx);
        mlp2_f32<1><<<BB * NN, 256, 0, stream>>>(feats1, idx, W1_1, b1_1, W2_1, b2_1,
                                                 mask, U2, T2, (float*)d_out);
    } else {
        mlp1_f64<0><<<BB * NN, 256, 0, stream>>>(x, idx, W1_0, b1_0, W2_0, b2_0,
                                                 W1_1, b1_1, tab, mask, U1, T1, W2d,
                                                 feats1, rm, U2, T2);
        knn2<<<BB * NN / 8, 512, 0, stream>>>(feats1, mask, rm, cu, nU, idx);
        mlp2_f32<0><<<BB * NN, 256, 0, stream>>>(feats1, idx, W1_1, b1_1, W2_1, b2_1,
                                                 mask, U2, T2, (float*)d_out);
    }
}

// Round 15
// 640.388 us; speedup vs baseline: 1.0936x; 1.0936x over previous
//
#include <hip/hip_runtime.h>
#include <math.h>

#define BB 64
#define NN 512
#define KK 16

// ---------------------------------------------------------------------------
// GELU helpers
// ---------------------------------------------------------------------------
__device__ __forceinline__ float gelu32(float x) {
    return 0.5f * x * (1.0f + erff(x * 0.70710678118654752440f));
}

// Table-based f64 GELU: erf(z) via nearest-node cubic Taylor, h = 1/64.
// Covers z <= 4.07 (|x| < 5.74); abs err ~8e-10 in range, ~3e-8 at the tail
// cutoff — ~1e7x below the knn2 rank-gap scale and invisible at bf16.
#define TAB_N 261
__device__ __forceinline__ double gelu64_tab(double x, const double2* s_tab) {
    double ax = fabs(x);
    if (ax >= 5.74) return x > 0.0 ? x : 0.0;
    double z = ax * 0.70710678118654752440;
    double u = z * 64.0;
    int i = (int)(u + 0.5);
    double zi = (double)i * (1.0 / 64.0);
    double d = z - zi;
    double2 t = s_tab[i];
    // erf(zi + d) = E + G*(d - zi*d^2 + (2*zi^2-1)/3 * d^3)
    double poly = d * (1.0 + d * (-zi + d * ((2.0 * zi * zi - 1.0) * (1.0 / 3.0))));
    double er = t.x + t.y * poly;
    double s = (x > 0.0) ? er : -er;
    return 0.5 * x * (1.0 + s);
}

// ---------------------------------------------------------------------------
// Wave-local top-17 extraction from 8 register-resident candidates per lane.
// No LDS, no barriers. Tie-break: lexicographic (dist, index), identical to
// jax.lax.top_k on negated distances. Winner-removal uses compile-time
// indices only (runtime-indexed reg arrays go to scratch — rule #20).
// ---------------------------------------------------------------------------
#define SELECT_TOP17(d, lane, OUT_STMT)                                        \
    for (int it = 0; it <= KK; ++it) {                                         \
        double bd = d[0];                                                      \
        int bi = lane;                                                         \
        _Pragma("unroll")                                                      \
        for (int i = 1; i < 8; ++i) {                                          \
            int m = lane + 64 * i;                                             \
            if (d[i] < bd) { bd = d[i]; bi = m; }                              \
        }                                                                      \
        for (int off = 32; off > 0; off >>= 1) {                               \
            double od = __shfl_xor(bd, off, 64);                               \
            int    oi = __shfl_xor(bi, off, 64);                               \
            if (od < bd || (od == bd && oi < bi)) { bd = od; bi = oi; }        \
        }                                                                      \
        const int wl = bi & 63, wsl = bi >> 6;                                 \
        _Pragma("unroll")                                                      \
        for (int i = 0; i < 8; ++i)                                            \
            if (lane == wl && i == wsl) d[i] = 1e300;                          \
        if (it > 0 && lane == 0) { OUT_STMT; }                                 \
    }

// ---------------------------------------------------------------------------
// Fused block-1 kNN + U1 projection + compaction + table build.
// Blocks [0, 4096): knn1 (8 queries per 512-thread block).
// Blocks [4096, 4096+uvb): uv1 — U1[row][j] = sum_c x[row][c]*W1a[c][j].
// Next 64 blocks: order-preserving compaction of unmasked indices per batch.
// Last block: erf table build.
// ---------------------------------------------------------------------------
__global__ __launch_bounds__(512) void knn1_uv1(const float* __restrict__ points,
                                                const int* __restrict__ mask,
                                                const float* __restrict__ x,
                                                const float* __restrict__ W1,
                                                int uvb,
                                                int* __restrict__ idx_out,
                                                double* __restrict__ U1,
                                                int* __restrict__ cu,
                                                int* __restrict__ nU,
                                                double2* __restrict__ g_tab) {
    __shared__ double sbuf[3 * NN];    // 12 KB
    const int tid = threadIdx.x;

    if (blockIdx.x < BB * NN / 8) {
        double (*pts)[NN] = (double (*)[NN])sbuf;
        const int b = blockIdx.x >> 6;          // 64 blocks per batch
        const int n0 = (blockIdx.x & 63) * 8;
        const int w = tid >> 6, lane = tid & 63;

        for (int e = tid; e < NN; e += 512) {
            double sh = (mask[b * NN + e] == 0) ? 999.0 : 0.0;
            const float* p = points + ((size_t)b * NN + e) * 3;
            pts[0][e] = (double)p[0] + sh;
            pts[1][e] = (double)p[1] + sh;
            pts[2][e] = (double)p[2] + sh;
        }
        __syncthreads();

        const int n = n0 + w;
        if (mask[b * NN + n] == 0) return;   // wave-uniform; no barriers below
        const double q0 = pts[0][n], q1 = pts[1][n], q2 = pts[2][n];
        double d[8];
        #pragma unroll
        for (int i = 0; i < 8; ++i) {
            int m = lane + 64 * i;
            double d0 = q0 - pts[0][m], d1 = q1 - pts[1][m], d2 = q2 - pts[2][m];
            d[i] = d0 * d0 + d1 * d1 + d2 * d2;   // +1e-5 const: ordering-invariant
        }

        int* orow = idx_out + (size_t)(b * NN + n) * KK;
        SELECT_TOP17(d, lane, orow[it - 1] = bi)
    } else if (blockIdx.x < BB * NN / 8 + uvb) {
        // uv1: rows row0..row0+7
        double (*xs)[32] = (double (*)[32])sbuf;
        const int row0 = (blockIdx.x - BB * NN / 8) * 8;
        if (tid < 256) xs[tid >> 5][tid & 31] = (double)x[(size_t)row0 * 32 + tid];
        __syncthreads();
        const int j = tid & 127;
        const int rr = tid >> 7;                 // 0..3, wave-uniform (2 waves/row)
        #pragma unroll
        for (int p = 0; p < 2; ++p) {
            const int r = p * 4 + rr;
            const int row = row0 + r;
            if (mask[row] != 0) {
                double acc = 0.0;
                #pragma unroll 4
                for (int c = 0; c < 32; ++c)
                    acc += xs[r][c] * (double)W1[c * 128 + j];
                U1[(size_t)row * 128 + j] = acc;
            }
        }
    } else if (blockIdx.x < BB * NN / 8 + uvb + BB) {
        // compaction: one batch per block, 512 threads = 512 candidates
        __shared__ int wcnt[8], woff[8];
        const int b = blockIdx.x - (BB * NN / 8 + uvb);
        const int w = tid >> 6, lane = tid & 63;
        const int bit = (mask[b * NN + tid] != 0) ? 1 : 0;
        unsigned long long bal = __ballot(bit);
        int pos = __popcll(bal & ((1ull << lane) - 1ull));
        if (lane == 0) wcnt[w] = __popcll(bal);
        __syncthreads();
        if (tid == 0) {
            int acc = 0;
            #pragma unroll
            for (int i = 0; i < 8; ++i) { woff[i] = acc; acc += wcnt[i]; }
            nU[b] = acc;
        }
        __syncthreads();
        if (bit) cu[b * NN + woff[w] + pos] = tid;
    } else {
        // erf table build
        for (int i = tid; i < TAB_N; i += 512) {
            double z = (double)i * (1.0 / 64.0);
            double2 e;
            e.x = erf(z);
            e.y = 1.12837916709551257390 * exp(-z * z);  // 2/sqrt(pi)*exp(-z^2)
            g_tab[i] = e;
        }
    }
}

// ---------------------------------------------------------------------------
// Block-1 MLP in f64 (LDS-table GELU) + fused rm precompute + fused U2 row
// projection for mlp2. Masked rows: exit immediately.
// ROUND-13 FORM — validated optimum (265 us, VALUBusy 58%). Three
// instruction-reduction variants (j-tiling r11, paired-W2 r12, T1/W2d r14)
// all regressed: the residual is dependent f64-FMA+gelu latency, and the
// tn loop / W2-f32 loads are L1-resident work that overlaps it for free.
// Register discipline: bounded unroll keeps natural VGPR demand under the
// (256,2) 128-VGPR cap (round 3: full unroll -> 9 GB scratch spill).
// LDS ~23 KB -> 6 blocks/CU.
// ---------------------------------------------------------------------------
template<int UV>
__global__ __launch_bounds__(256, 2) void mlp1_f64(const float* __restrict__ x,
                                                   const int* __restrict__ idx,
                                                   const float* __restrict__ W1,
                                                   const float* __restrict__ b1,
                                                   const float* __restrict__ W2,
                                                   const float* __restrict__ b2,
                                                   const float* __restrict__ W1n, // W1_1
                                                   const double2* __restrict__ g_tab,
                                                   const int* __restrict__ mask,
                                                   const double* __restrict__ U1,
                                                   double* __restrict__ feats_out,
                                                   double* __restrict__ rm,
                                                   float* __restrict__ U2) {
    const int C = 32;
    __shared__ double2 s_tab[TAB_N];               // 4.2 KB
    __shared__ double ctr[32];
    __shared__ __align__(16) double H1[KK][128];   // 16 KB
    __shared__ double part[4][64];                 //  2 KB
    __shared__ float f_row[64];                    // 256 B
    const int swz = ((blockIdx.x & 7) << 12) + (blockIdx.x >> 3);  // 32768/8 = 4096
    const int b = swz >> 9;
    const int bn = swz;
    const int tid = threadIdx.x;

    if (mask[bn] == 0) return;         // block-uniform; nothing downstream reads

    for (int i = tid; i < TAB_N; i += 256) s_tab[i] = g_tab[i];
    if (tid < C) ctr[tid] = (double)x[(size_t)bn * C + tid];
    __syncthreads();

    if constexpr (UV) {
        // layer 1 via per-point projections
        const int j = tid & 127;
        const int kb = (tid >> 7) * 8;
        double tn = (double)b1[j];
        #pragma unroll 4
        for (int c = 0; c < C; ++c)
            tn += ctr[c] * ((double)W1[(C + c) * 128 + j] - (double)W1[c * 128 + j]);
        #pragma unroll
        for (int kk = 0; kk < 8; ++kk) {
            int m = idx[bn * KK + kb + kk];
            double v = U1[(size_t)(b * NN + m) * 128 + j] + tn;
            H1[kb + kk][j] = gelu64_tab(v, s_tab);
        }
    } else {
        __shared__ double edg[KK][32];
        for (int e = tid; e < KK * C; e += 256) {
            int k = e >> 5, c = e & 31;
            int m = idx[bn * KK + k];
            edg[k][c] = (double)x[((size_t)b * NN + m) * C + c] - ctr[c];
        }
        __syncthreads();
        const int j = tid & 127;
        const int kb = (tid >> 7) * 8;
        double cterm = (double)b1[j];
        #pragma unroll 2
        for (int c = 0; c < C; ++c) cterm += ctr[c] * (double)W1[(C + c) * 128 + j];
        double acc[8];
        #pragma unroll
        for (int kk = 0; kk < 8; ++kk) acc[kk] = cterm;
        #pragma unroll 2
        for (int c = 0; c < C; ++c) {
            double w = (double)W1[c * 128 + j];
            #pragma unroll
            for (int kk = 0; kk < 8; ++kk) acc[kk] += edg[kb + kk][c] * w;
        }
        #pragma unroll
        for (int kk = 0; kk < 8; ++kk) H1[kb + kk][j] = gelu64_tab(acc[kk], s_tab);
    }
    __syncthreads();

    {   // layer 2: thread -> (j = tid&63, k-group g = tid>>6 of 4).
        // double2 H1 reads (b128) over c-pairs; accumulation order per acc[kk]
        // unchanged (c then c+1) -> bit-identical to scalar version.
        const int j = tid & 63;
        const int g = tid >> 6;
        const int kb = g * 4;
        double acc[4];
        #pragma unroll
        for (int kk = 0; kk < 4; ++kk) acc[kk] = (double)b2[j];
        #pragma unroll 2
        for (int c = 0; c < 128; c += 2) {
            double w0 = (double)W2[c * 64 + j];
            double w1 = (double)W2[(c + 1) * 64 + j];
            double2 h0 = *(const double2*)&H1[kb + 0][c];
            double2 h1 = *(const double2*)&H1[kb + 1][c];
            double2 h2 = *(const double2*)&H1[kb + 2][c];
            double2 h3 = *(const double2*)&H1[kb + 3][c];
            acc[0] += h0.x * w0; acc[0] += h0.y * w1;
            acc[1] += h1.x * w0; acc[1] += h1.y * w1;
            acc[2] += h2.x * w0; acc[2] += h2.y * w1;
            acc[3] += h3.x * w0; acc[3] += h3.y * w1;
        }
        double s = 0.0;
        #pragma unroll
        for (int kk = 0; kk < 4; ++kk) s += gelu64_tab(acc[kk], s_tab);
        part[g][j] = s;
    }
    __syncthreads();

    if (tid < 64) {   // wave 0: epilogue + fused rm (row is unmasked: sh=0)
        double s = (part[0][tid] + part[1][tid] + part[2][tid] + part[3][tid]) * 0.0625;
        feats_out[(size_t)bn * 64 + tid] = s;
        f_row[tid] = (float)s;
        double s2 = s * s;
        for (int off = 32; off > 0; off >>= 1) s2 += __shfl_xor(s2, off, 64);
        if (tid == 0) rm[bn] = s2;
    }
    if constexpr (UV) {   // fused uv2: U2[bn][j] = sum_c f_row[c]*W1a_1[c][j]
        __syncthreads();
        if (tid < 128) {
            float acc = 0.0f;
            #pragma unroll 4
            for (int c = 0; c < 64; ++c) acc += f_row[c] * W1n[c * 128 + tid];
            U2[(size_t)bn * 128 + tid] = acc;
        }
    }
}

// ---------------------------------------------------------------------------
// Block-2 kNN over COMPACTED unmasked candidates: F=64 f64 feats, top-17
// drop-first. 8 queries per 512-thread block; ~4 tiles (nU ~ 256). All
// candidates unmasked -> no shift terms; distances bit-identical to the
// uncompacted formula. Compacted order ascending -> tie-break identical.
// ---------------------------------------------------------------------------
__global__ __launch_bounds__(512) void knn2(const double* __restrict__ feats,
                                            const int* __restrict__ mask,
                                            const double* __restrict__ rm,
                                            const int* __restrict__ cu,
                                            const int* __restrict__ nU,
                                            int* __restrict__ idx_out) {
    __shared__ double tileT[64][65];   // [f][c], 33.3 KB
    __shared__ double qsh[8][64];      // 4 KB
    __shared__ double qrn[8];
    __shared__ int cI[NN];             // 2 KB
    __shared__ int s_nU;
    const int bid = ((blockIdx.x & 7) << 9) + (blockIdx.x >> 3);  // 4096/8 = 512
    const int b = bid >> 6;
    const int n0 = (bid & 63) * 8;
    const int tid = threadIdx.x;
    const int w = tid >> 6, lane = tid & 63;
    const int n = n0 + w;
    const int qm = mask[b * NN + n];   // wave-uniform

    if (tid == 0) s_nU = nU[b];
    for (int e = tid; e < NN; e += 512) cI[e] = cu[b * NN + e];
    qsh[w][lane] = feats[(size_t)(b * NN + n) * 64 + lane];
    if (lane == 0) qrn[w] = rm[b * NN + n];
    __syncthreads();

    const int nUl = s_nU;               // block-uniform
    const int ntiles = (nUl + 63) >> 6;

    double d[8];
    #pragma unroll
    for (int t = 0; t < 8; ++t) {
        d[t] = 1e300;
        if (t < ntiles) {               // block-uniform condition
            #pragma unroll
            for (int i = 0; i < 8; ++i) {
                int e = tid + 512 * i;
                int f = e & 63, c = e >> 6;
                int slot = t * 64 + c;
                if (slot < nUl)
                    tileT[f][c] = feats[(size_t)(b * NN + cI[slot]) * 64 + f];
            }
            __syncthreads();
            int slot = t * 64 + lane;
            if (qm && slot < nUl) {
                double a0 = 0.0, a1 = 0.0, a2 = 0.0, a3 = 0.0;
                for (int f = 0; f < 64; f += 4) {
                    a0 += qsh[w][f + 0] * tileT[f + 0][lane];
                    a1 += qsh[w][f + 1] * tileT[f + 1][lane];
                    a2 += qsh[w][f + 2] * tileT[f + 2][lane];
                    a3 += qsh[w][f + 3] * tileT[f + 3][lane];
                }
                double dot = (a0 + a1) + (a2 + a3);
                d[t] = qrn[w] + rm[b * NN + cI[slot]] - 2.0 * dot + 1e-5;
            }
            __syncthreads();
        }
    }

    if (qm) {
        int* orow = idx_out + (size_t)(b * NN + n) * KK;
        SELECT_TOP17(d, lane, orow[it - 1] = cI[bi])
    }
}

// ---------------------------------------------------------------------------
// Block-2 MLP in f32 + mean (round-10 layer 2 — validated fastest form).
// Masked rows: write zeros, skip all compute.
// ---------------------------------------------------------------------------
template<int UV>
__global__ __launch_bounds__(256, 2) void mlp2_f32(const double* __restrict__ feats,
                                                   const int* __restrict__ idx,
                                                   const float* __restrict__ W1,
                                                   const float* __restrict__ b1,
                                                   const float* __restrict__ W2,
                                                   const float* __restrict__ b2,
                                                   const int* __restrict__ mask,
                                                   const float* __restrict__ U2,
                                                   float* __restrict__ out) {
    const int C = 64;
    __shared__ float ctr[64];
    __shared__ __align__(16) float H1[KK][128];
    __shared__ float part[4][64];
    const int swz = ((blockIdx.x & 7) << 12) + (blockIdx.x >> 3);
    const int b = swz >> 9;
    const int bn = swz;
    const int tid = threadIdx.x;

    if (mask[bn] == 0) {               // block-uniform early exit
        if (tid < 64) out[(size_t)bn * 64 + tid] = 0.0f;
        return;
    }

    if (tid < C) ctr[tid] = (float)feats[(size_t)bn * C + tid];
    __syncthreads();

    if constexpr (UV) {
        const int j = tid & 127;
        const int kb = (tid >> 7) * 8;
        float tn = b1[j];
        #pragma unroll 4
        for (int c = 0; c < C; ++c)
            tn += ctr[c] * (W1[(C + c) * 128 + j] - W1[c * 128 + j]);
        #pragma unroll
        for (int kk = 0; kk < 8; ++kk) {
            int m = idx[bn * KK + kb + kk];
            H1[kb + kk][j] = gelu32(U2[(size_t)(b * NN + m) * 128 + j] + tn);
        }
    } else {
        __shared__ float edg[KK][64];
        for (int e = tid; e < KK * C; e += 256) {
            int k = e >> 6, c = e & 63;
            int m = idx[bn * KK + k];
            edg[k][c] = (float)feats[((size_t)b * NN + m) * C + c] - ctr[c];
        }
        __syncthreads();
        const int j = tid & 127;
        const int kb = (tid >> 7) * 8;
        float cterm = b1[j];
        #pragma unroll 2
        for (int c = 0; c < C; ++c) cterm += ctr[c] * W1[(C + c) * 128 + j];
        float acc[8];
        #pragma unroll
        for (int kk = 0; kk < 8; ++kk) acc[kk] = cterm;
        #pragma unroll 2
        for (int c = 0; c < C; ++c) {
            float w = W1[c * 128 + j];
            #pragma unroll
            for (int kk = 0; kk < 8; ++kk) acc[kk] += edg[kb + kk][c] * w;
        }
        #pragma unroll
        for (int kk = 0; kk < 8; ++kk) H1[kb + kk][j] = gelu32(acc[kk]);
    }
    __syncthreads();

    {   // layer 2 (round-10): float4 H1 reads over c-quads; order preserved.
        const int j = tid & 63;
        const int g = tid >> 6;
        const int kb = g * 4;
        float acc[4];
        #pragma unroll
        for (int kk = 0; kk < 4; ++kk) acc[kk] = b2[j];
        #pragma unroll 2
        for (int c = 0; c < 128; c += 4) {
            float w0 = W2[(c + 0) * 64 + j];
            float w1 = W2[(c + 1) * 64 + j];
            float w2 = W2[(c + 2) * 64 + j];
            float w3 = W2[(c + 3) * 64 + j];
            #pragma unroll
            for (int kk = 0; kk < 4; ++kk) {
                float4 h = *(const float4*)&H1[kb + kk][c];
                acc[kk] += h.x * w0; acc[kk] += h.y * w1;
                acc[kk] += h.z * w2; acc[kk] += h.w * w3;
            }
        }
        float s = 0.0f;
        #pragma unroll
        for (int kk = 0; kk < 4; ++kk) s += gelu32(acc[kk]);
        part[g][j] = s;
    }
    __syncthreads();

    if (tid < 64) {
        float s = (part[0][tid] + part[1][tid] + part[2][tid] + part[3][tid]) * 0.0625f;
        out[(size_t)bn * 64 + tid] = s;
    }
}

extern "C" void kernel_launch(void* const* d_in, const int* in_sizes, int n_in,
                              void* d_out, int out_size, void* d_ws, size_t ws_size,
                              hipStream_t stream) {
    const float* x      = (const float*)d_in[0];
    const float* points = (const float*)d_in[1];
    const int*   mask   = (const int*)d_in[2];
    const float* W1_0 = (const float*)d_in[3];
    const float* b1_0 = (const float*)d_in[4];
    const float* W2_0 = (const float*)d_in[5];
    const float* b2_0 = (const float*)d_in[6];
    const float* W1_1 = (const float*)d_in[7];
    const float* b1_1 = (const float*)d_in[8];
    const float* W2_1 = (const float*)d_in[9];
    const float* b2_1 = (const float*)d_in[10];

    char* ws = (char*)d_ws;
    const size_t off_tab   = 0;                      //   16 KB reserved
    const size_t off_idx   = 16384;                  //    2 MB
    const size_t off_feats = off_idx + 2097152;      // 16.8 MB
    const size_t off_rm    = off_feats + 16777216;   //  256 KB
    const size_t off_cu    = off_rm + 262144;        //  128 KB
    const size_t off_nu    = off_cu + 131072;        //    4 KB (64 ints + pad)
    const size_t off_u1    = off_nu + 4096;          // 33.5 MB
    const size_t off_u2    = off_u1 + 33554432;      // 16.8 MB
    const size_t need      = off_u2 + 16777216;      // ~69.6 MB total

    double2* tab    = (double2*)(ws + off_tab);
    int*     idx    = (int*)(ws + off_idx);
    double*  feats1 = (double*)(ws + off_feats);
    double*  rm     = (double*)(ws + off_rm);
    int*     cu     = (int*)(ws + off_cu);
    int*     nU     = (int*)(ws + off_nu);
    double*  U1     = (double*)(ws + off_u1);
    float*   U2     = (float*)(ws + off_u2);

    const int use_uv = (ws_size >= need) ? 1 : 0;
    const int uvb = use_uv ? BB * NN / 8 : 0;
    const int grid1 = BB * NN / 8 + uvb + BB + 1;   // knn + uv + compaction + tab

    knn1_uv1<<<grid1, 512, 0, stream>>>(points, mask, x, W1_0, uvb, idx, U1, cu, nU, tab);
    if (use_uv) {
        mlp1_f64<1><<<BB * NN, 256, 0, stream>>>(x, idx, W1_0, b1_0, W2_0, b2_0, W1_1,
                                                 tab, mask, U1, feats1, rm, U2);
        knn2<<<BB * NN / 8, 512, 0, stream>>>(feats1, mask, rm, cu, nU, idx);
        mlp2_f32<1><<<BB * NN, 256, 0, stream>>>(feats1, idx, W1_1, b1_1, W2_1, b2_1,
                                                 mask, U2, (float*)d_out);
    } else {
        mlp1_f64<0><<<BB * NN, 256, 0, stream>>>(x, idx, W1_0, b1_0, W2_0, b2_0, W1_1,
                                                 tab, mask, U1, feats1, rm, U2);
        knn2<<<BB * NN / 8, 512, 0, stream>>>(feats1, mask, rm, cu, nU, idx);
        mlp2_f32<0><<<BB * NN, 256, 0, stream>>>(feats1, idx, W1_1, b1_1, W2_1, b2_1,
                                                 mask, U2, (float*)d_out);
    }
}